// Round 21
// baseline (46.197 us; speedup 1.0000x reference)
//
#include <hip/hip_runtime.h>

// ISTFT via FFT. Two-frames-per-FFT pack, WAVE-LOCAL 1024-pt radix-4 Stockham.
// Round 21: TWO independent FFTs per wave (in-wave ILP-2). r17-r20 nulls leave
// one hypothesis: per-wave serial dependency stalls at ~3 waves/SIMD. Doubling
// independent work per wave at UNCHANGED occupancy (LDS 33.7KB/block -> still
// 4 blocks/CU; VGPR-capped ~3 waves/SIMD same as before) halves exposed
// latency per FFT. Per-FFT math/slot-maps/sync-pattern byte-identical to the
// r18 best kernel; all [ff] arrays unrolled -> compile-time indices.
//   frames[b,t,n] = Re{ sum_k X_t[k] e^{+2pi i kn/1024} } * hann[n]/1024
// Pack Z[k]=X1[k]+i*X2[k] -> frame 2m = Re z, 2m+1 = Im z; im at DC/Nyquist
// ZEROED (round-9 lesson). Stockham rule (proven r12-r20): stage S reads
// n=t+256k, writes 4Sp+q+Sk, twiddles tw[pS],tw[2pS],tw[3pS], +i convention.
// Twiddles via raw v_sin/v_cos (REVOLUTIONS: rev = T1/1024 exactly).
// Plane-split exchanges through one 4.2KB buffer per FFT; slot maps:
//   ex write1: 16l+4k+8*(l>>4) (b128); ex write2: 256(l>>4)+(l&15)+8*(l>>4)
//   +16r+64k (b32); reads: l+64j+264k. Wave-local DS is in-order.

#define BATCH    8
#define NFRAMES  2048
#define FREQ     513
#define OUTCOLS  524032
#define FRAMES_B ((size_t)16384 * 1024 * 2)    // 32 MB bf16 frames
#define WS_NEED  FRAMES_B

typedef __attribute__((ext_vector_type(2))) float f32x2;
typedef __attribute__((ext_vector_type(4))) float f32x4;
typedef __attribute__((ext_vector_type(4))) unsigned uint4v;

__device__ __forceinline__ unsigned short f2bf(float x) {
    unsigned u = __float_as_uint(x);
    return (unsigned short)((u + 0x7fffu + ((u >> 16) & 1u)) >> 16);
}

#define DSYNC() do { asm volatile("s_waitcnt lgkmcnt(0)" ::: "memory"); \
                     __builtin_amdgcn_sched_barrier(0); } while (0)

// Butterfly; twiddle base T1 (angle 2pi*T1/1024). v_sin/v_cos take REVOLUTIONS.
#define BFLY(IA, IB, IC, ID, T1, O0, O1, O2, O3)                              \
    {                                                                         \
        f32x2 apc = (IA) + (IC), amc = (IA) - (IC);                           \
        f32x2 bpd = (IB) + (ID), bmd = (IB) - (ID);                           \
        f32x2 jb  = (f32x2){-bmd[1], bmd[0]};   /* i*(b-d) */                 \
        float rev_ = (float)(T1) * (1.0f / 1024.0f);                          \
        float s1_ = __builtin_amdgcn_sinf(rev_);                              \
        float c1_ = __builtin_amdgcn_cosf(rev_);                              \
        float c2_ = fmaf(-2.0f * s1_, s1_, 1.0f), s2_ = 2.0f * s1_ * c1_;     \
        float c3_ = c2_ * c1_ - s2_ * s1_, s3_ = s2_ * c1_ + c2_ * s1_;       \
        f32x2 u1 = amc + jb, u2 = apc - bpd, u3 = amc - jb;                   \
        O0 = apc + bpd;                                                       \
        O1 = (f32x2){u1[0] * c1_ - u1[1] * s1_, u1[0] * s1_ + u1[1] * c1_};   \
        O2 = (f32x2){u2[0] * c2_ - u2[1] * s2_, u2[0] * s2_ + u2[1] * c2_};   \
        O3 = (f32x2){u3[0] * c3_ - u3[1] * s3_, u3[0] * s3_ + u3[1] * c3_};   \
    }

// ================= kernel 1: 4 waves x 2 FFTs per block =================
__global__ __launch_bounds__(256, 2) void ifft_wave7(
    const float* __restrict__ re, const float* __restrict__ im,
    const float* __restrict__ ola, unsigned short* __restrict__ frames) {
    __shared__ float L[4][2][1052];            // per-wave, per-FFT plane buffer

    const int tid  = threadIdx.x;
    const int l    = tid & 63;
    const int w    = tid >> 6;
    const int base = blockIdx.x * 16 + w * 4;  // 2 frame-pairs per wave
    float* PB[2] = { &L[w][0][0], &L[w][1][0] };

    // ---- stages 1+2 for both FFTs (loads of ff=1 overlap compute of ff=0) ----
    f32x4 wRe[2][4], wIm[2][4];
#pragma unroll
    for (int ff = 0; ff < 2; ++ff) {
        const int r0 = base + 2 * ff;
        const float* fre0 = re + (size_t)r0 * FREQ;
        const float* fim0 = im + (size_t)r0 * FREQ;
        const float* fre1 = fre0 + FREQ;
        const float* fim1 = fim0 + FREQ;

        f32x2 s1v[4][4];
#pragma unroll
        for (int j = 0; j < 4; ++j) {
            f32x2 in[4];
#pragma unroll
            for (int k = 0; k < 4; ++k) {
                int n  = l + 64 * j + 256 * k;
                int mm = (n <= 512) ? n : (1024 - n);
                float A1 = fre0[mm], B1 = fim0[mm];
                float A2 = fre1[mm], B2 = fim1[mm];
                if (n == 0 || n == 512) { B1 = 0.0f; B2 = 0.0f; }
                in[k] = (n <= 512) ? (f32x2){A1 - B2, B1 + A2}
                                   : (f32x2){A1 + B2, A2 - B1};
            }
            BFLY(in[0], in[1], in[2], in[3], l + 64 * j,
                 s1v[j][0], s1v[j][1], s1v[j][2], s1v[j][3]);
        }
#pragma unroll
        for (int r = 0; r < 4; ++r) {
            f32x2 o0, o1, o2, o3;
            BFLY(s1v[0][r], s1v[1][r], s1v[2][r], s1v[3][r], 4 * l,
                 o0, o1, o2, o3);
            wRe[ff][0][r] = o0[0]; wIm[ff][0][r] = o0[1];
            wRe[ff][1][r] = o1[0]; wIm[ff][1][r] = o1[1];
            wRe[ff][2][r] = o2[0]; wIm[ff][2][r] = o2[1];
            wRe[ff][3][r] = o3[0]; wIm[ff][3][r] = o3[1];
        }
    }

    // ---- exchange 1 (plane-split, both FFTs per sync) ----
    const int wb1 = 16 * l + 8 * (l >> 4);
#pragma unroll
    for (int ff = 0; ff < 2; ++ff)
#pragma unroll
        for (int k = 0; k < 4; ++k) *(f32x4*)&PB[ff][wb1 + 4 * k] = wRe[ff][k];
    DSYNC();
    float rr[2][4][4], ri[2][4][4];
#pragma unroll
    for (int ff = 0; ff < 2; ++ff)
#pragma unroll
        for (int j = 0; j < 4; ++j)
#pragma unroll
            for (int k = 0; k < 4; ++k)
                rr[ff][j][k] = PB[ff][l + 64 * j + 264 * k];
    DSYNC();   // Re reads retired before Im overwrites (WAR)
#pragma unroll
    for (int ff = 0; ff < 2; ++ff)
#pragma unroll
        for (int k = 0; k < 4; ++k) *(f32x4*)&PB[ff][wb1 + 4 * k] = wIm[ff][k];
    DSYNC();
#pragma unroll
    for (int ff = 0; ff < 2; ++ff)
#pragma unroll
        for (int j = 0; j < 4; ++j)
#pragma unroll
            for (int k = 0; k < 4; ++k)
                ri[ff][j][k] = PB[ff][l + 64 * j + 264 * k];
    DSYNC();   // Im reads retired before exchange-2 overwrites

    // ---- stages 3+4 for both FFTs ----
    float eRe[2][4][4], eIm[2][4][4];   // [ff][k][r]
#pragma unroll
    for (int ff = 0; ff < 2; ++ff) {
        f32x2 s3v[4][4];
#pragma unroll
        for (int j = 0; j < 4; ++j) {
            f32x2 a = (f32x2){rr[ff][j][0], ri[ff][j][0]};
            f32x2 b = (f32x2){rr[ff][j][1], ri[ff][j][1]};
            f32x2 c = (f32x2){rr[ff][j][2], ri[ff][j][2]};
            f32x2 d = (f32x2){rr[ff][j][3], ri[ff][j][3]};
            BFLY(a, b, c, d, (((l + 64 * j) >> 4) << 4),
                 s3v[j][0], s3v[j][1], s3v[j][2], s3v[j][3]);
        }
#pragma unroll
        for (int r = 0; r < 4; ++r) {
            f32x2 o0, o1, o2, o3;
            BFLY(s3v[0][r], s3v[1][r], s3v[2][r], s3v[3][r], ((l >> 4) << 6),
                 o0, o1, o2, o3);
            eRe[ff][0][r] = o0[0]; eIm[ff][0][r] = o0[1];
            eRe[ff][1][r] = o1[0]; eIm[ff][1][r] = o1[1];
            eRe[ff][2][r] = o2[0]; eIm[ff][2][r] = o2[1];
            eRe[ff][3][r] = o3[0]; eIm[ff][3][r] = o3[1];
        }
    }

    // ---- exchange 2 (plane-split, both FFTs per sync) ----
    const int wb2 = 256 * (l >> 4) + (l & 15) + 8 * (l >> 4);
#pragma unroll
    for (int ff = 0; ff < 2; ++ff)
#pragma unroll
        for (int k = 0; k < 4; ++k)
#pragma unroll
            for (int r = 0; r < 4; ++r)
                PB[ff][wb2 + 16 * r + 64 * k] = eRe[ff][k][r];
    DSYNC();
    float yR[2][4][4], yI[2][4][4];     // [ff][h][k]
#pragma unroll
    for (int ff = 0; ff < 2; ++ff)
#pragma unroll
        for (int h = 0; h < 4; ++h)
#pragma unroll
            for (int k = 0; k < 4; ++k)
                yR[ff][h][k] = PB[ff][l + 64 * h + 264 * k];
    DSYNC();
#pragma unroll
    for (int ff = 0; ff < 2; ++ff)
#pragma unroll
        for (int k = 0; k < 4; ++k)
#pragma unroll
            for (int r = 0; r < 4; ++r)
                PB[ff][wb2 + 16 * r + 64 * k] = eIm[ff][k][r];
    DSYNC();
#pragma unroll
    for (int ff = 0; ff < 2; ++ff)
#pragma unroll
        for (int h = 0; h < 4; ++h)
#pragma unroll
            for (int k = 0; k < 4; ++k)
                yI[ff][h][k] = PB[ff][l + 64 * h + 264 * k];
    DSYNC();

    // ---- stage 5 (unit twiddles) + hann + bf16 store, both FFTs ----
#pragma unroll
    for (int ff = 0; ff < 2; ++ff) {
        const int r0 = base + 2 * ff;
        unsigned short* fR = frames + (size_t)r0 * 1024;
        unsigned short* fI = fR + 1024;
#pragma unroll
        for (int h = 0; h < 4; ++h) {
            f32x2 a = (f32x2){yR[ff][h][0], yI[ff][h][0]};
            f32x2 b = (f32x2){yR[ff][h][1], yI[ff][h][1]};
            f32x2 c = (f32x2){yR[ff][h][2], yI[ff][h][2]};
            f32x2 d = (f32x2){yR[ff][h][3], yI[ff][h][3]};
            f32x2 apc = a + c, amc = a - c, bpd = b + d, bmd = b - d;
            f32x2 jb  = (f32x2){-bmd[1], bmd[0]};
            f32x2 y0 = apc + bpd, y1 = amc + jb, y2 = apc - bpd, y3 = amc - jb;
            int n0 = l + 64 * h;
            float h0 = sqrtf(ola[n0])       * (1.0f / 1024.0f);
            float h1 = sqrtf(ola[n0 + 256]) * (1.0f / 1024.0f);
            float h2 = sqrtf(ola[n0 + 512]) * (1.0f / 1024.0f);
            float h3 = sqrtf(ola[n0 + 768]) * (1.0f / 1024.0f);
            fR[n0]       = f2bf(y0[0] * h0);  fI[n0]       = f2bf(y0[1] * h0);
            fR[n0 + 256] = f2bf(y1[0] * h1);  fI[n0 + 256] = f2bf(y1[1] * h1);
            fR[n0 + 512] = f2bf(y2[0] * h2);  fI[n0 + 512] = f2bf(y2[1] * h2);
            fR[n0 + 768] = f2bf(y3[0] * h3);  fI[n0 + 768] = f2bf(y3[1] * h3);
        }
    }
}

// ================= kernel 2: OLA gather, 8 samples/thread =================
__global__ __launch_bounds__(256) void ola_fold8(
    const unsigned short* __restrict__ frames, const float* __restrict__ ola,
    float* __restrict__ out) {
    const int col0 = (blockIdx.x * 256 + threadIdx.x) * 8;
    if (col0 >= OUTCOLS) return;
    const int b  = blockIdx.y;
    const int s  = col0 + 512;     // uncropped sample index
    const int g  = s >> 8;
    const int ls = s & 255;        // multiple of 8

    float acc[8] = {0.f, 0.f, 0.f, 0.f, 0.f, 0.f, 0.f, 0.f};
    float wsm[8] = {0.f, 0.f, 0.f, 0.f, 0.f, 0.f, 0.f, 0.f};
#pragma unroll
    for (int j = 0; j < 4; ++j) {
        const int t = g - j;
        if (t >= 0 && t < NFRAMES) {
            uint4v u = *(const uint4v*)(frames + (((size_t)(b * NFRAMES + t)) << 10) + ls + 256 * j);
#pragma unroll
            for (int e = 0; e < 4; ++e) {
                acc[2 * e]     += __uint_as_float(u[e] << 16);
                acc[2 * e + 1] += __uint_as_float(u[e] & 0xffff0000u);
            }
            f32x4 o0 = *(const f32x4*)(ola + ls + 256 * j);
            f32x4 o1 = *(const f32x4*)(ola + ls + 256 * j + 4);
#pragma unroll
            for (int e = 0; e < 4; ++e) { wsm[e] += o0[e]; wsm[4 + e] += o1[e]; }
        }
    }
    f32x4 r0, r1;
#pragma unroll
    for (int e = 0; e < 4; ++e) {
        r0[e] = acc[e]     / fmaxf(wsm[e],     1e-11f);
        r1[e] = acc[4 + e] / fmaxf(wsm[4 + e], 1e-11f);
    }
    *(f32x4*)(out + (size_t)b * OUTCOLS + col0)     = r0;
    *(f32x4*)(out + (size_t)b * OUTCOLS + col0 + 4) = r1;
}

// ================= last-resort naive fallback (round-1, proven) =================
__global__ __launch_bounds__(256) void istft_naive(
    const float* __restrict__ re, const float* __restrict__ im,
    const float* __restrict__ Wr, const float* __restrict__ Wi,
    const float* __restrict__ ola, float* __restrict__ out) {
    const int g = blockIdx.x + 2, b = blockIdx.y, ls = threadIdx.x;
    __shared__ float s_fr[4][FREQ];
    __shared__ float s_fi[4][FREQ];
#pragma unroll
    for (int jj = 0; jj < 4; ++jj) {
        const int t = g - jj;
        const bool valid = (t >= 0 && t < NFRAMES);
        const size_t base = ((size_t)b * NFRAMES + (valid ? t : 0)) * FREQ;
        for (int k = ls; k < FREQ; k += 256) {
            const float f = (k == 0 || k == FREQ - 1) ? 1.0f : 2.0f;
            s_fr[jj][k] = valid ? re[base + k] * f : 0.0f;
            s_fi[jj][k] = valid ? im[base + k] * f : 0.0f;
        }
    }
    __syncthreads();
    const float* wr = Wr + ls;
    const float* wi = Wi + ls;
    float acc = 0.0f;
    for (int k = 0; k < FREQ; ++k) {
        const float* wrk = wr + (size_t)k * 1024;
        const float* wik = wi + (size_t)k * 1024;
#pragma unroll
        for (int jj = 0; jj < 4; ++jj) {
            acc = fmaf(wrk[jj * 256], s_fr[jj][k], acc);
            acc = fmaf(-wik[jj * 256], s_fi[jj][k], acc);
        }
    }
    float wsv = 0.0f;
#pragma unroll
    for (int jj = 0; jj < 4; ++jj) {
        const int t = g - jj;
        if (t >= 0 && t < NFRAMES) wsv += ola[ls + jj * 256];
    }
    wsv = fmaxf(wsv, 1e-11f);
    out[(size_t)b * OUTCOLS + (g * 256 + ls - 512)] = acc / wsv;
}

extern "C" void kernel_launch(void* const* d_in, const int* in_sizes, int n_in,
                              void* d_out, int out_size, void* d_ws, size_t ws_size,
                              hipStream_t stream) {
    const float* re  = (const float*)d_in[0];
    const float* im  = (const float*)d_in[1];
    const float* Wr  = (const float*)d_in[2];
    const float* Wi  = (const float*)d_in[3];
    const float* ola = (const float*)d_in[4];
    float* out = (float*)d_out;

    if (ws_size >= WS_NEED) {
        unsigned short* frames = (unsigned short*)d_ws;
        hipLaunchKernelGGL(ifft_wave7, dim3(1024), dim3(256), 0, stream,
                           re, im, ola, frames);
        hipLaunchKernelGGL(ola_fold8, dim3(256, BATCH), dim3(256), 0, stream,
                           frames, ola, out);
    } else {
        dim3 grid(2047, BATCH);
        hipLaunchKernelGGL(istft_naive, grid, dim3(256), 0, stream,
                           re, im, Wr, Wi, ola, out);
    }
}

// Round 22
// 37.275 us; speedup vs baseline: 1.2394x; 1.2394x over previous
//
#include <hip/hip_runtime.h>

// ISTFT via FFT. Two-frames-per-FFT pack, WAVE-LOCAL 1024-pt radix-4 Stockham,
// 4 independent wave-FFTs per 256-thread block, ZERO barriers (per-wave LDS
// slice + in-order DS + lgkmcnt), twiddles via RAW v_sin/v_cos (input in
// revolutions: rev = T1/1024 exactly — no range reduction, no libm), plane-
// split LDS exchanges (Re then Im through one reused 4.2KB buffer/wave).
// FINAL (= round-18 best, 37.2us measured): the r15-r21 sweep tested occupancy
// demand, VGPR caps, fence structure, load coalescing, block- and in-wave ILP,
// packed math, twiddle tables — this configuration is the measured optimum.
//   frames[b,t,n] = Re{ sum_k X_t[k] e^{+2pi i kn/1024} } * hann[n]/1024
// Pack Z[k]=X1[k]+i*X2[k] -> frame 2m = Re z, 2m+1 = Im z; im at DC/Nyquist
// ZEROED (round-9 lesson). Stockham rule (proven r12-r18): stage S reads
// n=t+256k, writes 4Sp+q+Sk, twiddles tw[pS],tw[2pS],tw[3pS], +i convention.
// Lane l owns: st1 vthreads {l+64j}; st2 {4l+r} (in-lane); st3 {l+64j};
// st4 {64(l>>4)+(l&15)+16r} (in-lane); st5 unit-twiddle + hann + bf16 store.
// Exchange slot for natural n: n + 8*(n>>8)  (conflict-free, proven r17/r18).

#define BATCH    8
#define NFRAMES  2048
#define FREQ     513
#define OUTCOLS  524032
#define FRAMES_B ((size_t)16384 * 1024 * 2)    // 32 MB bf16 frames
#define WS_NEED  FRAMES_B

typedef __attribute__((ext_vector_type(2))) float f32x2;
typedef __attribute__((ext_vector_type(4))) float f32x4;
typedef __attribute__((ext_vector_type(2))) unsigned uint2v;

__device__ __forceinline__ unsigned short f2bf(float x) {
    unsigned u = __float_as_uint(x);
    return (unsigned short)((u + 0x7fffu + ((u >> 16) & 1u)) >> 16);
}

#define DSYNC() do { asm volatile("s_waitcnt lgkmcnt(0)" ::: "memory"); \
                     __builtin_amdgcn_sched_barrier(0); } while (0)

// Butterfly; twiddle base T1 (angle 2pi*T1/1024). v_sin/v_cos take REVOLUTIONS:
// rev = T1/1024 in [0, 0.25]. w2/w3 by double/triple-angle chain.
#define BFLY(IA, IB, IC, ID, T1, O0, O1, O2, O3)                              \
    {                                                                         \
        f32x2 apc = (IA) + (IC), amc = (IA) - (IC);                           \
        f32x2 bpd = (IB) + (ID), bmd = (IB) - (ID);                           \
        f32x2 jb  = (f32x2){-bmd[1], bmd[0]};   /* i*(b-d) */                 \
        float rev_ = (float)(T1) * (1.0f / 1024.0f);                          \
        float s1_ = __builtin_amdgcn_sinf(rev_);                              \
        float c1_ = __builtin_amdgcn_cosf(rev_);                              \
        float c2_ = fmaf(-2.0f * s1_, s1_, 1.0f), s2_ = 2.0f * s1_ * c1_;     \
        float c3_ = c2_ * c1_ - s2_ * s1_, s3_ = s2_ * c1_ + c2_ * s1_;       \
        f32x2 u1 = amc + jb, u2 = apc - bpd, u3 = amc - jb;                   \
        O0 = apc + bpd;                                                       \
        O1 = (f32x2){u1[0] * c1_ - u1[1] * s1_, u1[0] * s1_ + u1[1] * c1_};   \
        O2 = (f32x2){u2[0] * c2_ - u2[1] * s2_, u2[0] * s2_ + u2[1] * c2_};   \
        O3 = (f32x2){u3[0] * c3_ - u3[1] * s3_, u3[0] * s3_ + u3[1] * c3_};   \
    }

// ================= kernel 1: 4 wave-local IFFTs per block =================
__global__ __launch_bounds__(256, 2) void ifft_wave4(
    const float* __restrict__ re, const float* __restrict__ im,
    const float* __restrict__ ola, unsigned short* __restrict__ frames) {
    __shared__ float L[4][1052];               // one 4.2KB plane buffer per wave

    const int tid = threadIdx.x;
    const int l   = tid & 63;
    const int w   = tid >> 6;
    const int r0  = (blockIdx.x * 4 + w) * 2;  // this wave's frame pair
    float* P = &L[w][0];

    const float* fre0 = re + (size_t)r0 * FREQ;
    const float* fim0 = im + (size_t)r0 * FREQ;
    const float* fre1 = fre0 + FREQ;
    const float* fim1 = fim0 + FREQ;

    // ---- stage 1 (S=1, vthreads l+64j): hermitian-packed global loads ----
    f32x2 s1v[4][4];
#pragma unroll
    for (int j = 0; j < 4; ++j) {
        f32x2 in[4];
#pragma unroll
        for (int k = 0; k < 4; ++k) {
            int n  = l + 64 * j + 256 * k;
            int mm = (n <= 512) ? n : (1024 - n);
            float A1 = fre0[mm], B1 = fim0[mm];
            float A2 = fre1[mm], B2 = fim1[mm];
            if (n == 0 || n == 512) { B1 = 0.0f; B2 = 0.0f; }  // DC/Nyq imag->0
            in[k] = (n <= 512) ? (f32x2){A1 - B2, B1 + A2}
                               : (f32x2){A1 + B2, A2 - B1};
        }
        BFLY(in[0], in[1], in[2], in[3], l + 64 * j,
             s1v[j][0], s1v[j][1], s1v[j][2], s1v[j][3]);
    }

    // ---- stage 2 (S=4, vthreads 4l+r, in-lane): out n = 16l + 4k + r ----
    f32x4 wRe[4], wIm[4];
#pragma unroll
    for (int r = 0; r < 4; ++r) {
        f32x2 o0, o1, o2, o3;
        BFLY(s1v[0][r], s1v[1][r], s1v[2][r], s1v[3][r], 4 * l, o0, o1, o2, o3);
        wRe[0][r] = o0[0]; wIm[0][r] = o0[1];
        wRe[1][r] = o1[0]; wIm[1][r] = o1[1];
        wRe[2][r] = o2[0]; wIm[2][r] = o2[1];
        wRe[3][r] = o3[0]; wIm[3][r] = o3[1];
    }

    // ---- exchange 1, Re plane: write b128 (slot 16l+4k+8*(l>>4)), read b32 ----
    {
        const int wb = 16 * l + 8 * (l >> 4);
#pragma unroll
        for (int k = 0; k < 4; ++k) *(f32x4*)&P[wb + 4 * k] = wRe[k];
    }
    DSYNC();
    float rr[4][4], ri[4][4];
#pragma unroll
    for (int j = 0; j < 4; ++j)
#pragma unroll
        for (int k = 0; k < 4; ++k) rr[j][k] = P[l + 64 * j + 264 * k];
    DSYNC();   // Re reads retired before Im overwrites (WAR)
    {
        const int wb = 16 * l + 8 * (l >> 4);
#pragma unroll
        for (int k = 0; k < 4; ++k) *(f32x4*)&P[wb + 4 * k] = wIm[k];
    }
    DSYNC();
#pragma unroll
    for (int j = 0; j < 4; ++j)
#pragma unroll
        for (int k = 0; k < 4; ++k) ri[j][k] = P[l + 64 * j + 264 * k];
    DSYNC();   // Im reads retired before exchange-2 overwrites

    // ---- stage 3 (S=16, vthreads l+64j) ----
    f32x2 s3v[4][4];
#pragma unroll
    for (int j = 0; j < 4; ++j) {
        f32x2 a = (f32x2){rr[j][0], ri[j][0]};
        f32x2 b = (f32x2){rr[j][1], ri[j][1]};
        f32x2 c = (f32x2){rr[j][2], ri[j][2]};
        f32x2 d = (f32x2){rr[j][3], ri[j][3]};
        BFLY(a, b, c, d, (((l + 64 * j) >> 4) << 4),
             s3v[j][0], s3v[j][1], s3v[j][2], s3v[j][3]);
    }

    // ---- stage 4 (S=64, in-lane): out n = 256(l>>4)+(l&15)+16r+64k ----
    float eRe[4][4], eIm[4][4];   // [k][r]
#pragma unroll
    for (int r = 0; r < 4; ++r) {
        f32x2 o0, o1, o2, o3;
        BFLY(s3v[0][r], s3v[1][r], s3v[2][r], s3v[3][r], ((l >> 4) << 6),
             o0, o1, o2, o3);
        eRe[0][r] = o0[0]; eIm[0][r] = o0[1];
        eRe[1][r] = o1[0]; eIm[1][r] = o1[1];
        eRe[2][r] = o2[0]; eIm[2][r] = o2[1];
        eRe[3][r] = o3[0]; eIm[3][r] = o3[1];
    }

    // ---- exchange 2, Re plane: write b32 (slot n+8*(l>>4)), read b32 ----
    DSYNC();
    {
        const int wb = 256 * (l >> 4) + (l & 15) + 8 * (l >> 4);
#pragma unroll
        for (int k = 0; k < 4; ++k)
#pragma unroll
            for (int r = 0; r < 4; ++r) P[wb + 16 * r + 64 * k] = eRe[k][r];
    }
    DSYNC();
    float yR[4][4], yI[4][4];     // [h][k]
#pragma unroll
    for (int h = 0; h < 4; ++h)
#pragma unroll
        for (int k = 0; k < 4; ++k) yR[h][k] = P[l + 64 * h + 264 * k];
    DSYNC();
    {
        const int wb = 256 * (l >> 4) + (l & 15) + 8 * (l >> 4);
#pragma unroll
        for (int k = 0; k < 4; ++k)
#pragma unroll
            for (int r = 0; r < 4; ++r) P[wb + 16 * r + 64 * k] = eIm[k][r];
    }
    DSYNC();
#pragma unroll
    for (int h = 0; h < 4; ++h)
#pragma unroll
        for (int k = 0; k < 4; ++k) yI[h][k] = P[l + 64 * h + 264 * k];
    DSYNC();

    // ---- stage 5 (S=256, unit twiddles) + hann + bf16 store ----
    unsigned short* fR = frames + (size_t)r0 * 1024;
    unsigned short* fI = fR + 1024;
#pragma unroll
    for (int h = 0; h < 4; ++h) {
        f32x2 a = (f32x2){yR[h][0], yI[h][0]};
        f32x2 b = (f32x2){yR[h][1], yI[h][1]};
        f32x2 c = (f32x2){yR[h][2], yI[h][2]};
        f32x2 d = (f32x2){yR[h][3], yI[h][3]};
        f32x2 apc = a + c, amc = a - c, bpd = b + d, bmd = b - d;
        f32x2 jb  = (f32x2){-bmd[1], bmd[0]};
        f32x2 y0 = apc + bpd, y1 = amc + jb, y2 = apc - bpd, y3 = amc - jb;
        int n0 = l + 64 * h;
        float h0 = sqrtf(ola[n0])       * (1.0f / 1024.0f);
        float h1 = sqrtf(ola[n0 + 256]) * (1.0f / 1024.0f);
        float h2 = sqrtf(ola[n0 + 512]) * (1.0f / 1024.0f);
        float h3 = sqrtf(ola[n0 + 768]) * (1.0f / 1024.0f);
        fR[n0]       = f2bf(y0[0] * h0);  fI[n0]       = f2bf(y0[1] * h0);
        fR[n0 + 256] = f2bf(y1[0] * h1);  fI[n0 + 256] = f2bf(y1[1] * h1);
        fR[n0 + 512] = f2bf(y2[0] * h2);  fI[n0 + 512] = f2bf(y2[1] * h2);
        fR[n0 + 768] = f2bf(y3[0] * h3);  fI[n0 + 768] = f2bf(y3[1] * h3);
    }
}

// ================= kernel 2: OLA gather, 4 samples/thread =================
__global__ __launch_bounds__(256) void ola_fold4(
    const unsigned short* __restrict__ frames, const float* __restrict__ ola,
    float* __restrict__ out) {
    const int col0 = (blockIdx.x * 256 + threadIdx.x) * 4;
    if (col0 >= OUTCOLS) return;
    const int b  = blockIdx.y;
    const int s  = col0 + 512;     // uncropped sample index
    const int g  = s >> 8;
    const int ls = s & 255;        // multiple of 4

    float a0 = 0.f, a1 = 0.f, a2 = 0.f, a3 = 0.f;
    float w0 = 0.f, w1 = 0.f, w2 = 0.f, w3 = 0.f;
#pragma unroll
    for (int j = 0; j < 4; ++j) {
        const int t = g - j;
        if (t >= 0 && t < NFRAMES) {
            uint2v u = *(const uint2v*)(frames + (((size_t)(b * NFRAMES + t)) << 10) + ls + 256 * j);
            a0 += __uint_as_float(u[0] << 16);
            a1 += __uint_as_float(u[0] & 0xffff0000u);
            a2 += __uint_as_float(u[1] << 16);
            a3 += __uint_as_float(u[1] & 0xffff0000u);
            f32x4 o = *(const f32x4*)(ola + ls + 256 * j);
            w0 += o[0]; w1 += o[1]; w2 += o[2]; w3 += o[3];
        }
    }
    f32x4 r = (f32x4){a0 / fmaxf(w0, 1e-11f), a1 / fmaxf(w1, 1e-11f),
                      a2 / fmaxf(w2, 1e-11f), a3 / fmaxf(w3, 1e-11f)};
    *(f32x4*)(out + (size_t)b * OUTCOLS + col0) = r;
}

// ================= last-resort naive fallback (round-1, proven) =================
__global__ __launch_bounds__(256) void istft_naive(
    const float* __restrict__ re, const float* __restrict__ im,
    const float* __restrict__ Wr, const float* __restrict__ Wi,
    const float* __restrict__ ola, float* __restrict__ out) {
    const int g = blockIdx.x + 2, b = blockIdx.y, ls = threadIdx.x;
    __shared__ float s_fr[4][FREQ];
    __shared__ float s_fi[4][FREQ];
#pragma unroll
    for (int jj = 0; jj < 4; ++jj) {
        const int t = g - jj;
        const bool valid = (t >= 0 && t < NFRAMES);
        const size_t base = ((size_t)b * NFRAMES + (valid ? t : 0)) * FREQ;
        for (int k = ls; k < FREQ; k += 256) {
            const float f = (k == 0 || k == FREQ - 1) ? 1.0f : 2.0f;
            s_fr[jj][k] = valid ? re[base + k] * f : 0.0f;
            s_fi[jj][k] = valid ? im[base + k] * f : 0.0f;
        }
    }
    __syncthreads();
    const float* wr = Wr + ls;
    const float* wi = Wi + ls;
    float acc = 0.0f;
    for (int k = 0; k < FREQ; ++k) {
        const float* wrk = wr + (size_t)k * 1024;
        const float* wik = wi + (size_t)k * 1024;
#pragma unroll
        for (int jj = 0; jj < 4; ++jj) {
            acc = fmaf(wrk[jj * 256], s_fr[jj][k], acc);
            acc = fmaf(-wik[jj * 256], s_fi[jj][k], acc);
        }
    }
    float wsv = 0.0f;
#pragma unroll
    for (int jj = 0; jj < 4; ++jj) {
        const int t = g - jj;
        if (t >= 0 && t < NFRAMES) wsv += ola[ls + jj * 256];
    }
    wsv = fmaxf(wsv, 1e-11f);
    out[(size_t)b * OUTCOLS + (g * 256 + ls - 512)] = acc / wsv;
}

extern "C" void kernel_launch(void* const* d_in, const int* in_sizes, int n_in,
                              void* d_out, int out_size, void* d_ws, size_t ws_size,
                              hipStream_t stream) {
    const float* re  = (const float*)d_in[0];
    const float* im  = (const float*)d_in[1];
    const float* Wr  = (const float*)d_in[2];
    const float* Wi  = (const float*)d_in[3];
    const float* ola = (const float*)d_in[4];
    float* out = (float*)d_out;

    if (ws_size >= WS_NEED) {
        unsigned short* frames = (unsigned short*)d_ws;
        hipLaunchKernelGGL(ifft_wave4, dim3(2048), dim3(256), 0, stream,
                           re, im, ola, frames);
        hipLaunchKernelGGL(ola_fold4, dim3(512, BATCH), dim3(256), 0, stream,
                           frames, ola, out);
    } else {
        dim3 grid(2047, BATCH);
        hipLaunchKernelGGL(istft_naive, grid, dim3(256), 0, stream,
                           re, im, Wr, Wi, ola, out);
    }
}